// Round 5
// baseline (164.013 us; speedup 1.0000x reference)
//
#include <hip/hip_runtime.h>
#include <math.h>

#define NPTS   2048
#define BATCH  32
#define M_POLY 815
#define NSPLIT 8
#define GPB    4
#define RSTR   192
#define BN_EPS 1e-5f
#define TRI(j) ((j)*(33-(j))/2)
#define NBLK   256

// chunk ci -> (L=e1+e2, k0=e2 block start, c=e0, qoff4=logical word of Q block)
__device__ __forceinline__ bool decode_chunk(int ci, int& Lo, int& k0o, int& co, int& qo) {
    int idx = 0, qoff = 0;
    for (int l = 0; l < 16; ++l) {
        const int nb   = (l + 4) >> 2;
        const int cmin = (l == 0) ? 1 : 0;
        const int nc   = 16 - l - cmin;
        for (int kb = 0; kb < nb; ++kb) {
            if (ci < idx + nc) {
                Lo = l; k0o = kb * 4; co = cmin + (ci - idx);
                qo = 32 + qoff + kb * 4;
                return true;
            }
            idx += nc;
        }
        qoff += nb * 4;
    }
    return false;
}

__device__ __forceinline__ void grid_barrier(int* slot) {
    __syncthreads();
    __threadfence();                       // publish this block's global writes
    if (threadIdx.x == 0) {
        __hip_atomic_fetch_add(slot, 1, __ATOMIC_ACQ_REL, __HIP_MEMORY_SCOPE_AGENT);
        while (__hip_atomic_load(slot, __ATOMIC_ACQUIRE, __HIP_MEMORY_SCOPE_AGENT) < NBLK)
            __builtin_amdgcn_s_sleep(2);
    }
    __syncthreads();
}

__global__ __launch_bounds__(256, 1) void fused_kernel(
    const float* __restrict__ x,
    const float* __restrict__ W1, const float* __restrict__ b1,
    const float* __restrict__ g1, const float* __restrict__ be1,
    const float* __restrict__ rm1, const float* __restrict__ rv1,
    const float* __restrict__ W2, const float* __restrict__ b2,
    const float* __restrict__ g2, const float* __restrict__ be2,
    const float* __restrict__ rm2, const float* __restrict__ rv2,
    const float* __restrict__ W3, const float* __restrict__ b3,
    const float* __restrict__ g3, const float* __restrict__ be3,
    const float* __restrict__ rm3, const float* __restrict__ rv3,
    const float* __restrict__ W4, const float* __restrict__ b4,
    float* __restrict__ out,
    float* __restrict__ part, float* __restrict__ h1, float* __restrict__ h2,
    int* __restrict__ bar)
{
    __shared__ __align__(16) float S[64 * RSTR];   // 49,152 B, aliased per phase
    const int t   = threadIdx.x;
    const int blk = blockIdx.x;

    // ================= Phase 1: Chebyshev moments (R4 structure) =============
    {
        const int sb = blk & 7;       // k-split
        const int b  = blk >> 3;      // batch
        const int nn = t & 63;
        const int qq = t >> 6;
        const int sw = 4 * (nn & 7);
        const int base = nn * RSTR;

        int L, k0, c, qoff4;
        decode_chunk(t, L, k0, c, qoff4);
        const bool dual = (t >= 61 && t <= 63);
        int L2 = 0, k02 = 0, c2 = 0, qoff42 = 32;
        if (dual) decode_chunk(256 + (t - 61), L2, k02, c2, qoff42);

        int qx[8], tx[8], q2x[8], t2x[8];
        #pragma unroll
        for (int r = 0; r < 8; ++r) {
            qx[r]  = qoff4  ^ (4 * r);
            tx[r]  = c      ^ (4 * r);
            q2x[r] = qoff42 ^ (4 * r);
            t2x[r] = c2     ^ (4 * r);
        }

        float a[4]  = {0.f, 0.f, 0.f, 0.f};
        float a2[4] = {0.f, 0.f, 0.f, 0.f};
        const float* xb = x + (size_t)b * 3 * NPTS;

        for (int g = 0; g < GPB; ++g) {
            if (g) __syncthreads();
            {   // phase A: build swizzled tables
                const int n = sb * 256 + g * 64 + nn;
                const float x1 = xb[NPTS + n], x2 = xb[2 * NPTS + n];
                float T1r[16], T2r[16];
                T1r[0] = 1.f; T1r[1] = x1;
                #pragma unroll
                for (int k = 2; k < 16; ++k) T1r[k] = 2.f * x1 * T1r[k-1] - T1r[k-2];
                T2r[0] = 1.f; T2r[1] = x2;
                #pragma unroll
                for (int k = 2; k < 16; ++k) T2r[k] = 2.f * x2 * T2r[k-1] - T2r[k-2];

                #define QVAL(SS,E) (((E) <= (SS)) ? T1r[((SS)-(E)) & 15] * T2r[(E) & 15] : 0.f)
                #define ROWQ(SS, QO) { \
                    _Pragma("unroll") \
                    for (int blk2 = 0; blk2 < ((SS)+4)/4; ++blk2) { \
                        float4 v; \
                        v.x = QVAL(SS, 4*blk2+0); v.y = QVAL(SS, 4*blk2+1); \
                        v.z = QVAL(SS, 4*blk2+2); v.w = QVAL(SS, 4*blk2+3); \
                        *(float4*)&S[base + ((32 + (QO) + 4*blk2) ^ sw)] = v; } }

                if (qq == 0) {
                    const float x0 = xb[n];
                    float T0r[16];
                    T0r[0] = 1.f; T0r[1] = x0;
                    #pragma unroll
                    for (int k = 2; k < 16; ++k) T0r[k] = 2.f * x0 * T0r[k-1] - T0r[k-2];
                    #pragma unroll
                    for (int blk2 = 0; blk2 < 8; ++blk2) {
                        float4 v;
                        v.x = (4*blk2+0 < 16) ? T0r[(4*blk2+0) & 15] : 0.f;
                        v.y = (4*blk2+1 < 16) ? T0r[(4*blk2+1) & 15] : 0.f;
                        v.z = (4*blk2+2 < 16) ? T0r[(4*blk2+2) & 15] : 0.f;
                        v.w = (4*blk2+3 < 16) ? T0r[(4*blk2+3) & 15] : 0.f;
                        *(float4*)&S[base + ((4*blk2) ^ sw)] = v;
                    }
                    ROWQ(0, 0)  ROWQ(1, 4)  ROWQ(2, 8)  ROWQ(3, 12)
                } else if (qq == 1) {
                    ROWQ(4, 16) ROWQ(5, 24) ROWQ(6, 32) ROWQ(7, 40) ROWQ(8, 48)
                } else if (qq == 2) {
                    ROWQ(9, 60) ROWQ(10, 72) ROWQ(11, 84) ROWQ(12, 96)
                } else {
                    ROWQ(13, 112) ROWQ(14, 128) ROWQ(15, 144)
                }
                #undef ROWQ
                #undef QVAL
            }
            __syncthreads();

            // phase B: accumulate
            for (int n8 = 0; n8 < 8; ++n8) {
                const float* rp0 = &S[n8 * 8 * RSTR];
                #pragma unroll
                for (int r = 0; r < 8; ++r) {
                    const float* rp = rp0 + r * RSTR;
                    const float t0v = rp[tx[r]];
                    const float4 q = *(const float4*)&rp[qx[r]];
                    a[0] = fmaf(t0v, q.x, a[0]);
                    a[1] = fmaf(t0v, q.y, a[1]);
                    a[2] = fmaf(t0v, q.z, a[2]);
                    a[3] = fmaf(t0v, q.w, a[3]);
                    if (dual) {
                        const float u0 = rp[t2x[r]];
                        const float4 p2 = *(const float4*)&rp[q2x[r]];
                        a2[0] = fmaf(u0, p2.x, a2[0]);
                        a2[1] = fmaf(u0, p2.y, a2[1]);
                        a2[2] = fmaf(u0, p2.z, a2[2]);
                        a2[3] = fmaf(u0, p2.w, a2[3]);
                    }
                }
            }
        }

        float* pb = part + ((size_t)b * NSPLIT + sb) * M_POLY;
        {
            const int D  = c + L;
            const int mb = D * (D + 1) * (D + 2) / 6 - 1 + L * (L + 1) / 2;
            const int nv = (L - k0 + 1 < 4) ? (L - k0 + 1) : 4;
            #pragma unroll
            for (int i = 0; i < 4; ++i)
                if (i < nv) pb[mb + k0 + i] = a[i];
        }
        if (dual) {
            const int D  = c2 + L2;
            const int mb = D * (D + 1) * (D + 2) / 6 - 1 + L2 * (L2 + 1) / 2;
            const int nv = (L2 - k02 + 1 < 4) ? (L2 - k02 + 1) : 4;
            #pragma unroll
            for (int i = 0; i < 4; ++i)
                if (i < nv) pb[mb + k02 + i] = a2[i];
        }
    }

    grid_barrier(bar + 0);

    // ================= Phase 2: l1 = 815->512 + BN + ReLU ====================
    {
        const int og = blk & 7;       // og = blk%8 -> one W1 slice per XCD L2
        const int b  = blk >> 3;
        float* fs  = S;               // [816]
        float* red = S + 816;         // [4][64]

        #pragma unroll
        for (int mi = 0; mi < 4; ++mi) {
            const int m = t + mi * 256;
            if (m < 815) {
                float s0 = 0.f;
                #pragma unroll
                for (int sp = 0; sp < NSPLIT; ++sp)
                    s0 += part[((size_t)b * NSPLIT + sp) * M_POLY + m];
                fs[m] = s0 * (1.0f / (float)NPTS);
            } else if (m == 815) {
                fs[815] = 0.f;
            }
        }
        __syncthreads();

        const int o  = og * 64 + (t & 63);
        const int kg = t >> 6;
        const int kb = kg * 204;      // 4*204 = 816, fs[815]=0 nulls pad
        float acc = 0.f;
        #pragma unroll 4
        for (int kk = 0; kk < 204; ++kk) {
            const int k  = kb + kk;
            const int kr = (k < 815) ? k : 814;
            acc = fmaf(fs[k], W1[(size_t)kr * 512 + o], acc);
        }
        red[kg * 64 + (t & 63)] = acc;
        __syncthreads();

        if (t < 64) {
            const float dot = red[t] + red[64 + t] + red[128 + t] + red[192 + t];
            const int oo = og * 64 + t;
            const float v = (dot + b1[oo] - rm1[oo]) * g1[oo] * rsqrtf(rv1[oo] + BN_EPS) + be1[oo];
            h1[b * 512 + oo] = v > 0.f ? v : 0.f;
        }
    }

    grid_barrier(bar + 1);

    // ================= Phase 3: l2 = 512->256 + BN + ReLU (blocks 0..127) ====
    if (blk < 128) {
        const int og = blk & 3;       // blk%8 fixes blk&3 per XCD -> one W2 slice
        const int b  = blk >> 2;
        float* hs  = S;               // [512]
        float* red = S + 512;         // [4][64]

        hs[t] = h1[b * 512 + t];
        hs[256 + t] = h1[b * 512 + 256 + t];
        __syncthreads();

        const int o  = og * 64 + (t & 63);
        const int kg = t >> 6;
        const int kb = kg * 128;
        float acc = 0.f;
        #pragma unroll 8
        for (int kk = 0; kk < 128; ++kk)
            acc = fmaf(hs[kb + kk], W2[(size_t)(kb + kk) * 256 + o], acc);
        red[kg * 64 + (t & 63)] = acc;
        __syncthreads();

        if (t < 64) {
            const float dot = red[t] + red[64 + t] + red[128 + t] + red[192 + t];
            const int oo = og * 64 + t;
            const float v = (dot + b2[oo] - rm2[oo]) * g2[oo] * rsqrtf(rv2[oo] + BN_EPS) + be2[oo];
            h2[b * 256 + oo] = v > 0.f ? v : 0.f;
        }
    }

    grid_barrier(bar + 2);

    // ================= Phase 4: l3+l4 (blocks 0..31) =========================
    if (blk < 32) {
        const int b = blk;
        float* hs   = S;              // [256]
        float* red3 = S + 256;        // [2][128]
        float* h3s  = S + 512;        // [128]
        float* red4 = S + 640;        // [4][64]

        hs[t] = h2[b * 256 + t];
        __syncthreads();

        {   // L3: 128 o x 2 kg (chain 128)
            const int o  = t & 127;
            const int kg = t >> 7;
            const int kb = kg * 128;
            float acc = 0.f;
            #pragma unroll 8
            for (int kk = 0; kk < 128; ++kk)
                acc = fmaf(hs[kb + kk], W3[(size_t)(kb + kk) * 128 + o], acc);
            red3[kg * 128 + o] = acc;
        }
        __syncthreads();
        if (t < 128) {
            const float dot = red3[t] + red3[128 + t];
            const float v = (dot + b3[t] - rm3[t]) * g3[t] * rsqrtf(rv3[t] + BN_EPS) + be3[t];
            h3s[t] = v > 0.f ? v : 0.f;
        }
        __syncthreads();

        {   // L4: 40 o (o<64 lanes, clamp) x 4 kg (chain 32)
            const int o  = t & 63;
            const int om = (o < 40) ? o : 39;
            const int kg = t >> 6;
            const int kb = kg * 32;
            float acc = 0.f;
            #pragma unroll
            for (int kk = 0; kk < 32; ++kk)
                acc = fmaf(h3s[kb + kk], W4[(size_t)(kb + kk) * 40 + om], acc);
            red4[kg * 64 + o] = acc;
        }
        __syncthreads();
        if (t < 40) {
            const float dot = red4[t] + red4[64 + t] + red4[128 + t] + red4[192 + t];
            out[b * 40 + t] = dot + b4[t];
        }
    }
}

extern "C" void kernel_launch(void* const* d_in, const int* in_sizes, int n_in,
                              void* d_out, int out_size, void* d_ws, size_t ws_size,
                              hipStream_t stream) {
    const float* x  = (const float*)d_in[0];
    const float* W1 = (const float*)d_in[2];
    const float* b1 = (const float*)d_in[3];
    const float* g1 = (const float*)d_in[4];
    const float* be1= (const float*)d_in[5];
    const float* rm1= (const float*)d_in[6];
    const float* rv1= (const float*)d_in[7];
    const float* W2 = (const float*)d_in[8];
    const float* b2 = (const float*)d_in[9];
    const float* g2 = (const float*)d_in[10];
    const float* be2= (const float*)d_in[11];
    const float* rm2= (const float*)d_in[12];
    const float* rv2= (const float*)d_in[13];
    const float* W3 = (const float*)d_in[14];
    const float* b3 = (const float*)d_in[15];
    const float* g3 = (const float*)d_in[16];
    const float* be3= (const float*)d_in[17];
    const float* rm3= (const float*)d_in[18];
    const float* rv3= (const float*)d_in[19];
    const float* W4 = (const float*)d_in[20];
    const float* b4 = (const float*)d_in[21];
    float* out = (float*)d_out;

    // ws layout: bar (64 B) | part (32*8*815 f32) | h1 (32*512) | h2 (32*256)
    int*   bar  = (int*)d_ws;
    float* part = (float*)((char*)d_ws + 64);
    float* h1   = part + (size_t)BATCH * NSPLIT * M_POLY;
    float* h2   = h1 + (size_t)BATCH * 512;

    hipMemsetAsync(bar, 0, 64, stream);
    fused_kernel<<<NBLK, 256, 0, stream>>>(x,
        W1, b1, g1, be1, rm1, rv1,
        W2, b2, g2, be2, rm2, rv2,
        W3, b3, g3, be3, rm3, rv3,
        W4, b4, out, part, h1, h2, bar);
}

// Round 6
// 81.504 us; speedup vs baseline: 2.0123x; 2.0123x over previous
//
#include <hip/hip_runtime.h>
#include <math.h>

#define NPTS   2048
#define BATCH  32
#define M_POLY 815
#define GPB    2
#define NSPLIT 16            // 2048 / (64*GPB)
#define RSTR   192
#define BN_EPS 1e-5f
#define NBLK   256           // fused MLP grid

// ---------------------------------------------------------------------------
// Moments kernel — UNCHANGED from R4 (measured good: 512 blocks, 2/CU).
// ---------------------------------------------------------------------------
__device__ __forceinline__ bool decode_chunk(int ci, int& Lo, int& k0o, int& co, int& qo) {
    int idx = 0, qoff = 0;
    for (int l = 0; l < 16; ++l) {
        const int nb   = (l + 4) >> 2;
        const int cmin = (l == 0) ? 1 : 0;
        const int nc   = 16 - l - cmin;
        for (int kb = 0; kb < nb; ++kb) {
            if (ci < idx + nc) {
                Lo = l; k0o = kb * 4; co = cmin + (ci - idx);
                qo = 32 + qoff + kb * 4;
                return true;
            }
            idx += nc;
        }
        qoff += nb * 4;
    }
    return false;
}

__global__ __launch_bounds__(256) void moments_kernel(
    const float* __restrict__ x,      // (B, 3, N)
    float*       __restrict__ part)   // (B, NSPLIT, M_POLY)
{
    __shared__ __align__(16) float P[64 * RSTR];   // 49,152 B
    const int t  = threadIdx.x;
    const int sb = blockIdx.x;
    const int b  = blockIdx.y;
    const int nn = t & 63;
    const int qq = t >> 6;
    const int sw = 4 * (nn & 7);
    const int base = nn * RSTR;

    int L, k0, c, qoff4;
    decode_chunk(t, L, k0, c, qoff4);
    const bool dual = (t >= 61 && t <= 63);
    int L2 = 0, k02 = 0, c2 = 0, qoff42 = 32;
    if (dual) decode_chunk(256 + (t - 61), L2, k02, c2, qoff42);

    int qx[8], tx[8], q2x[8], t2x[8];
    #pragma unroll
    for (int r = 0; r < 8; ++r) {
        qx[r]  = qoff4  ^ (4 * r);
        tx[r]  = c      ^ (4 * r);
        q2x[r] = qoff42 ^ (4 * r);
        t2x[r] = c2     ^ (4 * r);
    }

    float a[4]  = {0.f, 0.f, 0.f, 0.f};
    float a2[4] = {0.f, 0.f, 0.f, 0.f};
    const float* xb = x + (size_t)b * 3 * NPTS;

    for (int g = 0; g < GPB; ++g) {
        if (g) __syncthreads();
        {
            const int n = (sb * GPB + g) * 64 + nn;
            const float x1 = xb[NPTS + n], x2 = xb[2 * NPTS + n];
            float T1r[16], T2r[16];
            T1r[0] = 1.f; T1r[1] = x1;
            #pragma unroll
            for (int k = 2; k < 16; ++k) T1r[k] = 2.f * x1 * T1r[k-1] - T1r[k-2];
            T2r[0] = 1.f; T2r[1] = x2;
            #pragma unroll
            for (int k = 2; k < 16; ++k) T2r[k] = 2.f * x2 * T2r[k-1] - T2r[k-2];

            #define QVAL(SS,E) (((E) <= (SS)) ? T1r[((SS)-(E)) & 15] * T2r[(E) & 15] : 0.f)
            #define ROWQ(SS, QO) { \
                _Pragma("unroll") \
                for (int blk2 = 0; blk2 < ((SS)+4)/4; ++blk2) { \
                    float4 v; \
                    v.x = QVAL(SS, 4*blk2+0); v.y = QVAL(SS, 4*blk2+1); \
                    v.z = QVAL(SS, 4*blk2+2); v.w = QVAL(SS, 4*blk2+3); \
                    *(float4*)&P[base + ((32 + (QO) + 4*blk2) ^ sw)] = v; } }

            if (qq == 0) {
                const float x0 = xb[n];
                float T0r[16];
                T0r[0] = 1.f; T0r[1] = x0;
                #pragma unroll
                for (int k = 2; k < 16; ++k) T0r[k] = 2.f * x0 * T0r[k-1] - T0r[k-2];
                #pragma unroll
                for (int blk2 = 0; blk2 < 8; ++blk2) {
                    float4 v;
                    v.x = (4*blk2+0 < 16) ? T0r[(4*blk2+0) & 15] : 0.f;
                    v.y = (4*blk2+1 < 16) ? T0r[(4*blk2+1) & 15] : 0.f;
                    v.z = (4*blk2+2 < 16) ? T0r[(4*blk2+2) & 15] : 0.f;
                    v.w = (4*blk2+3 < 16) ? T0r[(4*blk2+3) & 15] : 0.f;
                    *(float4*)&P[base + ((4*blk2) ^ sw)] = v;
                }
                ROWQ(0, 0)  ROWQ(1, 4)  ROWQ(2, 8)  ROWQ(3, 12)
            } else if (qq == 1) {
                ROWQ(4, 16) ROWQ(5, 24) ROWQ(6, 32) ROWQ(7, 40) ROWQ(8, 48)
            } else if (qq == 2) {
                ROWQ(9, 60) ROWQ(10, 72) ROWQ(11, 84) ROWQ(12, 96)
            } else {
                ROWQ(13, 112) ROWQ(14, 128) ROWQ(15, 144)
            }
            #undef ROWQ
            #undef QVAL
        }
        __syncthreads();

        for (int n8 = 0; n8 < 8; ++n8) {
            const float* rp0 = &P[n8 * 8 * RSTR];
            #pragma unroll
            for (int r = 0; r < 8; ++r) {
                const float* rp = rp0 + r * RSTR;
                const float t0v = rp[tx[r]];
                const float4 q = *(const float4*)&rp[qx[r]];
                a[0] = fmaf(t0v, q.x, a[0]);
                a[1] = fmaf(t0v, q.y, a[1]);
                a[2] = fmaf(t0v, q.z, a[2]);
                a[3] = fmaf(t0v, q.w, a[3]);
                if (dual) {
                    const float u0 = rp[t2x[r]];
                    const float4 p2 = *(const float4*)&rp[q2x[r]];
                    a2[0] = fmaf(u0, p2.x, a2[0]);
                    a2[1] = fmaf(u0, p2.y, a2[1]);
                    a2[2] = fmaf(u0, p2.z, a2[2]);
                    a2[3] = fmaf(u0, p2.w, a2[3]);
                }
            }
        }
    }

    float* pb = part + ((size_t)b * NSPLIT + sb) * M_POLY;
    {
        const int D  = c + L;
        const int mb = D * (D + 1) * (D + 2) / 6 - 1 + L * (L + 1) / 2;
        const int nv = (L - k0 + 1 < 4) ? (L - k0 + 1) : 4;
        #pragma unroll
        for (int i = 0; i < 4; ++i)
            if (i < nv) pb[mb + k0 + i] = a[i];
    }
    if (dual) {
        const int D  = c2 + L2;
        const int mb = D * (D + 1) * (D + 2) / 6 - 1 + L2 * (L2 + 1) / 2;
        const int nv = (L2 - k02 + 1 < 4) ? (L2 - k02 + 1) : 4;
        #pragma unroll
        for (int i = 0; i < 4; ++i)
            if (i < nv) pb[mb + k02 + i] = a2[i];
    }
}

// ---------------------------------------------------------------------------
// Grid barrier, fixed: RELAXED polls + s_sleep backoff; one acq_rel agent
// fence before arrive (publish) and one after exit (invalidate stale lines).
// Cache maintenance happens ONCE per barrier, not per poll (the R5 bug).
// ---------------------------------------------------------------------------
__device__ __forceinline__ void grid_barrier(int* slot) {
    __syncthreads();
    if (threadIdx.x == 0) {
        __threadfence();   // release: publish this block's global writes
        __hip_atomic_fetch_add(slot, 1, __ATOMIC_RELAXED, __HIP_MEMORY_SCOPE_AGENT);
        while (__hip_atomic_load(slot, __ATOMIC_RELAXED, __HIP_MEMORY_SCOPE_AGENT) < NBLK)
            __builtin_amdgcn_s_sleep(8);
        __threadfence();   // acquire: discard stale cached lines
    }
    __syncthreads();
}

// ---------------------------------------------------------------------------
// Fused MLP: l1 (256 blocks) -> barrier -> l2 (128 blocks) -> barrier ->
// l3+l4 (32 blocks). All phase math identical to R5 (numerically verified).
// ---------------------------------------------------------------------------
__global__ __launch_bounds__(256) void mlp_fused_kernel(
    const float* __restrict__ part,
    const float* __restrict__ W1, const float* __restrict__ b1,
    const float* __restrict__ g1, const float* __restrict__ be1,
    const float* __restrict__ rm1, const float* __restrict__ rv1,
    const float* __restrict__ W2, const float* __restrict__ b2,
    const float* __restrict__ g2, const float* __restrict__ be2,
    const float* __restrict__ rm2, const float* __restrict__ rv2,
    const float* __restrict__ W3, const float* __restrict__ b3,
    const float* __restrict__ g3, const float* __restrict__ be3,
    const float* __restrict__ rm3, const float* __restrict__ rv3,
    const float* __restrict__ W4, const float* __restrict__ b4,
    float* __restrict__ out,
    float* __restrict__ h1, float* __restrict__ h2,
    int* __restrict__ bar)
{
    __shared__ float S[1152];
    const int t   = threadIdx.x;
    const int blk = blockIdx.x;

    // ---------------- l1: 815->512 + BN + ReLU (all 256 blocks) -------------
    {
        const int og = blk & 7;      // blk%8 == XCD id -> one W1 slice per L2
        const int b  = blk >> 3;
        float* fs  = S;              // [816]
        float* red = S + 816;        // [4][64]

        #pragma unroll
        for (int mi = 0; mi < 4; ++mi) {
            const int m = t + mi * 256;
            if (m < 815) {
                float s0 = 0.f;
                #pragma unroll
                for (int sp = 0; sp < NSPLIT; ++sp)
                    s0 += part[((size_t)b * NSPLIT + sp) * M_POLY + m];
                fs[m] = s0 * (1.0f / (float)NPTS);
            } else if (m == 815) {
                fs[815] = 0.f;
            }
        }
        __syncthreads();

        const int o  = og * 64 + (t & 63);
        const int kg = t >> 6;
        const int kb = kg * 204;     // 4*204 = 816; fs[815]=0 nulls pad
        float acc = 0.f;
        #pragma unroll 4
        for (int kk = 0; kk < 204; ++kk) {
            const int k  = kb + kk;
            const int kr = (k < 815) ? k : 814;
            acc = fmaf(fs[k], W1[(size_t)kr * 512 + o], acc);
        }
        red[kg * 64 + (t & 63)] = acc;
        __syncthreads();

        if (t < 64) {
            const float dot = red[t] + red[64 + t] + red[128 + t] + red[192 + t];
            const int oo = og * 64 + t;
            const float v = (dot + b1[oo] - rm1[oo]) * g1[oo] * rsqrtf(rv1[oo] + BN_EPS) + be1[oo];
            h1[b * 512 + oo] = v > 0.f ? v : 0.f;
        }
    }

    grid_barrier(bar + 0);

    // ---------------- l2: 512->256 + BN + ReLU (blocks 0..127) --------------
    if (blk < 128) {
        const int og = blk & 3;
        const int b  = blk >> 2;
        float* hs  = S;              // [512]
        float* red = S + 512;        // [4][64]

        hs[t] = h1[b * 512 + t];
        hs[256 + t] = h1[b * 512 + 256 + t];
        __syncthreads();

        const int o  = og * 64 + (t & 63);
        const int kg = t >> 6;
        const int kb = kg * 128;
        float acc = 0.f;
        #pragma unroll 8
        for (int kk = 0; kk < 128; ++kk)
            acc = fmaf(hs[kb + kk], W2[(size_t)(kb + kk) * 256 + o], acc);
        red[kg * 64 + (t & 63)] = acc;
        __syncthreads();

        if (t < 64) {
            const float dot = red[t] + red[64 + t] + red[128 + t] + red[192 + t];
            const int oo = og * 64 + t;
            const float v = (dot + b2[oo] - rm2[oo]) * g2[oo] * rsqrtf(rv2[oo] + BN_EPS) + be2[oo];
            h2[b * 256 + oo] = v > 0.f ? v : 0.f;
        }
    }

    grid_barrier(bar + 1);

    // ---------------- l3+l4 (blocks 0..31) ----------------------------------
    if (blk < 32) {
        const int b = blk;
        float* hs   = S;             // [256]
        float* red3 = S + 256;       // [2][128]
        float* h3s  = S + 512;       // [128]
        float* red4 = S + 640;       // [4][64]

        hs[t] = h2[b * 256 + t];
        __syncthreads();

        {
            const int o  = t & 127;
            const int kg = t >> 7;
            const int kb = kg * 128;
            float acc = 0.f;
            #pragma unroll 8
            for (int kk = 0; kk < 128; ++kk)
                acc = fmaf(hs[kb + kk], W3[(size_t)(kb + kk) * 128 + o], acc);
            red3[kg * 128 + o] = acc;
        }
        __syncthreads();
        if (t < 128) {
            const float dot = red3[t] + red3[128 + t];
            const float v = (dot + b3[t] - rm3[t]) * g3[t] * rsqrtf(rv3[t] + BN_EPS) + be3[t];
            h3s[t] = v > 0.f ? v : 0.f;
        }
        __syncthreads();

        {
            const int o  = t & 63;
            const int om = (o < 40) ? o : 39;
            const int kg = t >> 6;
            const int kb = kg * 32;
            float acc = 0.f;
            #pragma unroll
            for (int kk = 0; kk < 32; ++kk)
                acc = fmaf(h3s[kb + kk], W4[(size_t)(kb + kk) * 40 + om], acc);
            red4[kg * 64 + o] = acc;
        }
        __syncthreads();
        if (t < 40) {
            const float dot = red4[t] + red4[64 + t] + red4[128 + t] + red4[192 + t];
            out[b * 40 + t] = dot + b4[t];
        }
    }
}

extern "C" void kernel_launch(void* const* d_in, const int* in_sizes, int n_in,
                              void* d_out, int out_size, void* d_ws, size_t ws_size,
                              hipStream_t stream) {
    const float* x  = (const float*)d_in[0];
    const float* W1 = (const float*)d_in[2];
    const float* b1 = (const float*)d_in[3];
    const float* g1 = (const float*)d_in[4];
    const float* be1= (const float*)d_in[5];
    const float* rm1= (const float*)d_in[6];
    const float* rv1= (const float*)d_in[7];
    const float* W2 = (const float*)d_in[8];
    const float* b2 = (const float*)d_in[9];
    const float* g2 = (const float*)d_in[10];
    const float* be2= (const float*)d_in[11];
    const float* rm2= (const float*)d_in[12];
    const float* rv2= (const float*)d_in[13];
    const float* W3 = (const float*)d_in[14];
    const float* b3 = (const float*)d_in[15];
    const float* g3 = (const float*)d_in[16];
    const float* be3= (const float*)d_in[17];
    const float* rm3= (const float*)d_in[18];
    const float* rv3= (const float*)d_in[19];
    const float* W4 = (const float*)d_in[20];
    const float* b4 = (const float*)d_in[21];
    float* out = (float*)d_out;

    // ws: bar (64 B) | part (32*16*815 f32) | h1 (32*512) | h2 (32*256)
    int*   bar  = (int*)d_ws;
    float* part = (float*)((char*)d_ws + 64);
    float* h1   = part + (size_t)BATCH * NSPLIT * M_POLY;
    float* h2   = h1 + (size_t)BATCH * 512;

    hipMemsetAsync(bar, 0, 64, stream);
    moments_kernel<<<dim3(NSPLIT, BATCH), 256, 0, stream>>>(x, part);
    mlp_fused_kernel<<<NBLK, 256, 0, stream>>>(part,
        W1, b1, g1, be1, rm1, rv1,
        W2, b2, g2, be2, rm2, rv2,
        W3, b3, g3, be3, rm3, rv3,
        W4, b4, out, h1, h2, bar);
}

// Round 7
// 61.213 us; speedup vs baseline: 2.6794x; 1.3315x over previous
//
#include <hip/hip_runtime.h>
#include <math.h>

#define NPTS   2048
#define BATCH  32
#define M_POLY 815
#define NSPLIT 8
#define RSTR   192
#define HALF_LDS (64 * RSTR)     // 12288 floats per half-table
#define BN_EPS 1e-5f

// chunk ci -> (L=e1+e2, k0=e2 block start, c=e0, qoff4=logical word of Q block)
__device__ __forceinline__ bool decode_chunk(int ci, int& Lo, int& k0o, int& co, int& qo) {
    int idx = 0, qoff = 0;
    for (int l = 0; l < 16; ++l) {
        const int nb   = (l + 4) >> 2;
        const int cmin = (l == 0) ? 1 : 0;
        const int nc   = 16 - l - cmin;
        for (int kb = 0; kb < nb; ++kb) {
            if (ci < idx + nc) {
                Lo = l; k0o = kb * 4; co = cmin + (ci - idx);
                qo = 32 + qoff + kb * 4;
                return true;
            }
            idx += nc;
        }
        qoff += nb * 4;
    }
    return false;
}

// Batch-local barrier: <=8 arrivals per 64B-strided counter. Release fence
// before arrive, relaxed polls + s_sleep, acquire fence on exit (R6 pattern).
__device__ __forceinline__ void bar_arrive(int* slot) {
    __syncthreads();
    if (threadIdx.x == 0) {
        __threadfence();     // publish this block's global writes
        __hip_atomic_fetch_add(slot, 1, __ATOMIC_RELAXED, __HIP_MEMORY_SCOPE_AGENT);
    }
}
__device__ __forceinline__ void bar_wait(int* slot, int target) {
    if (threadIdx.x == 0) {
        while (__hip_atomic_load(slot, __ATOMIC_RELAXED, __HIP_MEMORY_SCOPE_AGENT) < target)
            __builtin_amdgcn_s_sleep(2);
        __threadfence();     // discard stale cached lines
    }
    __syncthreads();
}

__global__ __launch_bounds__(512) void fused_kernel(
    const float* __restrict__ x,
    const float* __restrict__ W1, const float* __restrict__ b1,
    const float* __restrict__ g1, const float* __restrict__ be1,
    const float* __restrict__ rm1, const float* __restrict__ rv1,
    const float* __restrict__ W2, const float* __restrict__ b2,
    const float* __restrict__ g2, const float* __restrict__ be2,
    const float* __restrict__ rm2, const float* __restrict__ rv2,
    const float* __restrict__ W3, const float* __restrict__ b3,
    const float* __restrict__ g3, const float* __restrict__ be3,
    const float* __restrict__ rm3, const float* __restrict__ rv3,
    const float* __restrict__ W4, const float* __restrict__ b4,
    float* __restrict__ out,
    float* __restrict__ part, float* __restrict__ h1, float* __restrict__ h2,
    int* __restrict__ bar)
{
    __shared__ __align__(16) float S[2 * HALF_LDS];   // 98,304 B -> 1 block/CU
    const int t    = threadIdx.x;
    const int blk  = blockIdx.x;
    const int b    = blk >> 3;
    const int role = blk & 7;

    // ============ Phase 1: moments, points [role*256, role*256+256) =========
    // Two 256-thread halves, each with its own 64-point table (R4 math).
    {
        const int hh = t >> 8;
        const int tt = t & 255;
        const int nn = tt & 63;
        const int qq = tt >> 6;
        const int sw = 4 * (nn & 7);
        const int base = nn * RSTR;
        float* Sh = S + hh * HALF_LDS;

        int L, k0, c, qoff4;
        decode_chunk(tt, L, k0, c, qoff4);
        const bool dual = (tt >= 61 && tt <= 63);
        int L2 = 0, k02 = 0, c2 = 0, qoff42 = 32;
        if (dual) decode_chunk(256 + (tt - 61), L2, k02, c2, qoff42);

        int qx[8], tx[8], q2x[8], t2x[8];
        #pragma unroll
        for (int rr = 0; rr < 8; ++rr) {
            qx[rr]  = qoff4  ^ (4 * rr);
            tx[rr]  = c      ^ (4 * rr);
            q2x[rr] = qoff42 ^ (4 * rr);
            t2x[rr] = c2     ^ (4 * rr);
        }

        float a[4]  = {0.f, 0.f, 0.f, 0.f};
        float a2[4] = {0.f, 0.f, 0.f, 0.f};
        const float* xb = x + (size_t)b * 3 * NPTS;

        for (int g = 0; g < 2; ++g) {
            if (g) __syncthreads();
            {   // phase A: build swizzled table for this half's 64 points
                const int n = role * 256 + hh * 128 + g * 64 + nn;
                const float x1 = xb[NPTS + n], x2 = xb[2 * NPTS + n];
                float T1r[16], T2r[16];
                T1r[0] = 1.f; T1r[1] = x1;
                #pragma unroll
                for (int k = 2; k < 16; ++k) T1r[k] = 2.f * x1 * T1r[k-1] - T1r[k-2];
                T2r[0] = 1.f; T2r[1] = x2;
                #pragma unroll
                for (int k = 2; k < 16; ++k) T2r[k] = 2.f * x2 * T2r[k-1] - T2r[k-2];

                #define QVAL(SS,E) (((E) <= (SS)) ? T1r[((SS)-(E)) & 15] * T2r[(E) & 15] : 0.f)
                #define ROWQ(SS, QO) { \
                    _Pragma("unroll") \
                    for (int blk2 = 0; blk2 < ((SS)+4)/4; ++blk2) { \
                        float4 v; \
                        v.x = QVAL(SS, 4*blk2+0); v.y = QVAL(SS, 4*blk2+1); \
                        v.z = QVAL(SS, 4*blk2+2); v.w = QVAL(SS, 4*blk2+3); \
                        *(float4*)&Sh[base + ((32 + (QO) + 4*blk2) ^ sw)] = v; } }

                if (qq == 0) {
                    const float x0 = xb[n];
                    float T0r[16];
                    T0r[0] = 1.f; T0r[1] = x0;
                    #pragma unroll
                    for (int k = 2; k < 16; ++k) T0r[k] = 2.f * x0 * T0r[k-1] - T0r[k-2];
                    #pragma unroll
                    for (int blk2 = 0; blk2 < 8; ++blk2) {
                        float4 v;
                        v.x = (4*blk2+0 < 16) ? T0r[(4*blk2+0) & 15] : 0.f;
                        v.y = (4*blk2+1 < 16) ? T0r[(4*blk2+1) & 15] : 0.f;
                        v.z = (4*blk2+2 < 16) ? T0r[(4*blk2+2) & 15] : 0.f;
                        v.w = (4*blk2+3 < 16) ? T0r[(4*blk2+3) & 15] : 0.f;
                        *(float4*)&Sh[base + ((4*blk2) ^ sw)] = v;
                    }
                    ROWQ(0, 0)  ROWQ(1, 4)  ROWQ(2, 8)  ROWQ(3, 12)
                } else if (qq == 1) {
                    ROWQ(4, 16) ROWQ(5, 24) ROWQ(6, 32) ROWQ(7, 40) ROWQ(8, 48)
                } else if (qq == 2) {
                    ROWQ(9, 60) ROWQ(10, 72) ROWQ(11, 84) ROWQ(12, 96)
                } else {
                    ROWQ(13, 112) ROWQ(14, 128) ROWQ(15, 144)
                }
                #undef ROWQ
                #undef QVAL
            }
            __syncthreads();

            // phase B: accumulate over this half's 64 points
            for (int n8 = 0; n8 < 8; ++n8) {
                const float* rp0 = &Sh[n8 * 8 * RSTR];
                #pragma unroll
                for (int rr = 0; rr < 8; ++rr) {
                    const float* rp = rp0 + rr * RSTR;
                    const float t0v = rp[tx[rr]];
                    const float4 q = *(const float4*)&rp[qx[rr]];
                    a[0] = fmaf(t0v, q.x, a[0]);
                    a[1] = fmaf(t0v, q.y, a[1]);
                    a[2] = fmaf(t0v, q.z, a[2]);
                    a[3] = fmaf(t0v, q.w, a[3]);
                    if (dual) {
                        const float u0 = rp[t2x[rr]];
                        const float4 p2 = *(const float4*)&rp[q2x[rr]];
                        a2[0] = fmaf(u0, p2.x, a2[0]);
                        a2[1] = fmaf(u0, p2.y, a2[1]);
                        a2[2] = fmaf(u0, p2.z, a2[2]);
                        a2[3] = fmaf(u0, p2.w, a2[3]);
                    }
                }
            }
        }

        // combine the two halves (reuse S[0..1035] as scratch)
        __syncthreads();
        if (hh == 1) {
            #pragma unroll
            for (int i = 0; i < 4; ++i) S[tt * 4 + i] = a[i];
            if (dual) {
                #pragma unroll
                for (int i = 0; i < 4; ++i) S[1024 + (tt - 61) * 4 + i] = a2[i];
            }
        }
        __syncthreads();
        if (hh == 0) {
            float* pb = part + ((size_t)b * NSPLIT + role) * M_POLY;
            {
                const int D  = c + L;
                const int mb = D * (D + 1) * (D + 2) / 6 - 1 + L * (L + 1) / 2;
                const int nv = (L - k0 + 1 < 4) ? (L - k0 + 1) : 4;
                #pragma unroll
                for (int i = 0; i < 4; ++i)
                    if (i < nv) pb[mb + k0 + i] = a[i] + S[tt * 4 + i];
            }
            if (dual) {
                const int D  = c2 + L2;
                const int mb = D * (D + 1) * (D + 2) / 6 - 1 + L2 * (L2 + 1) / 2;
                const int nv = (L2 - k02 + 1 < 4) ? (L2 - k02 + 1) : 4;
                #pragma unroll
                for (int i = 0; i < 4; ++i)
                    if (i < nv) pb[mb + k02 + i] = a2[i] + S[1024 + (tt - 61) * 4 + i];
            }
        }
    }

    int* bar0 = bar + (0 * BATCH + b) * 16;
    int* bar1 = bar + (1 * BATCH + b) * 16;
    int* bar2 = bar + (2 * BATCH + b) * 16;

    bar_arrive(bar0);
    bar_wait(bar0, 8);      // all 8 part slices of batch b ready

    // ============ Phase 2: l1 = 815->512 + BN + ReLU (role = og) ============
    {
        float* fs  = S;               // [816]
        float* red = S + 816;         // [8][64]

        {
            float s0 = 0.f;
            #pragma unroll
            for (int sp = 0; sp < NSPLIT; ++sp)
                s0 += part[((size_t)b * NSPLIT + sp) * M_POLY + t];
            fs[t] = s0 * (1.0f / (float)NPTS);
            const int m2 = t + 512;
            if (m2 < 815) {
                float s1 = 0.f;
                #pragma unroll
                for (int sp = 0; sp < NSPLIT; ++sp)
                    s1 += part[((size_t)b * NSPLIT + sp) * M_POLY + m2];
                fs[m2] = s1 * (1.0f / (float)NPTS);
            } else if (m2 == 815) {
                fs[815] = 0.f;
            }
        }
        __syncthreads();

        const int o  = role * 64 + (t & 63);
        const int kg = t >> 6;
        const int kb = kg * 102;      // 8*102 = 816; fs[815]=0 nulls pad
        float acc = 0.f;
        #pragma unroll 6
        for (int kk = 0; kk < 102; ++kk) {
            const int k  = kb + kk;
            const int kr = (k < 815) ? k : 814;
            acc = fmaf(fs[k], W1[(size_t)kr * 512 + o], acc);
        }
        red[kg * 64 + (t & 63)] = acc;
        __syncthreads();

        if (t < 64) {
            float dot = 0.f;
            #pragma unroll
            for (int j = 0; j < 8; ++j) dot += red[j * 64 + t];
            const int oo = role * 64 + t;
            const float v = (dot + b1[oo] - rm1[oo]) * g1[oo] * rsqrtf(rv1[oo] + BN_EPS) + be1[oo];
            h1[b * 512 + oo] = v > 0.f ? v : 0.f;
        }
    }

    bar_arrive(bar1);
    if (role >= 4) return;            // arrive-and-exit, no spin
    bar_wait(bar1, 8);                // all of h1[b] ready

    // ============ Phase 3: l2 = 512->256 + BN + ReLU (roles 0..3) ===========
    {
        float* hs  = S;               // [512]
        float* red = S + 512;         // [8][64]

        hs[t] = h1[b * 512 + t];
        __syncthreads();

        const int o  = role * 64 + (t & 63);
        const int kg = t >> 6;
        const int kb = kg * 64;
        float acc = 0.f;
        #pragma unroll 8
        for (int kk = 0; kk < 64; ++kk)
            acc = fmaf(hs[kb + kk], W2[(size_t)(kb + kk) * 256 + o], acc);
        red[kg * 64 + (t & 63)] = acc;
        __syncthreads();

        if (t < 64) {
            float dot = 0.f;
            #pragma unroll
            for (int j = 0; j < 8; ++j) dot += red[j * 64 + t];
            const int oo = role * 64 + t;
            const float v = (dot + b2[oo] - rm2[oo]) * g2[oo] * rsqrtf(rv2[oo] + BN_EPS) + be2[oo];
            h2[b * 256 + oo] = v > 0.f ? v : 0.f;
        }
    }

    bar_arrive(bar2);
    if (role >= 1) return;            // arrive-and-exit
    bar_wait(bar2, 4);                // all of h2[b] ready

    // ============ Phase 4: l3+l4 (role 0 only) ==============================
    {
        float* hs   = S;              // [256]
        float* red3 = S + 256;        // [4][128]
        float* h3s  = S + 768;        // [128]
        float* red4 = S + 896;        // [8][64]

        if (t < 256) hs[t] = h2[b * 256 + t];
        __syncthreads();

        {   // L3: 128 outputs x 4 k-groups of 64
            const int o  = t & 127;
            const int kg = t >> 7;
            const int kb = kg * 64;
            float acc = 0.f;
            #pragma unroll 8
            for (int kk = 0; kk < 64; ++kk)
                acc = fmaf(hs[kb + kk], W3[(size_t)(kb + kk) * 128 + o], acc);
            red3[kg * 128 + o] = acc;
        }
        __syncthreads();
        if (t < 128) {
            const float dot = red3[t] + red3[128 + t] + red3[256 + t] + red3[384 + t];
            const float v = (dot + b3[t] - rm3[t]) * g3[t] * rsqrtf(rv3[t] + BN_EPS) + be3[t];
            h3s[t] = v > 0.f ? v : 0.f;
        }
        __syncthreads();

        {   // L4: 40 outputs (o<64 lanes, clamp) x 8 k-groups of 16
            const int o  = t & 63;
            const int om = (o < 40) ? o : 39;
            const int kg = t >> 6;
            const int kb = kg * 16;
            float acc = 0.f;
            #pragma unroll
            for (int kk = 0; kk < 16; ++kk)
                acc = fmaf(h3s[kb + kk], W4[(size_t)(kb + kk) * 40 + om], acc);
            red4[kg * 64 + o] = acc;
        }
        __syncthreads();
        if (t < 40) {
            float dot = 0.f;
            #pragma unroll
            for (int j = 0; j < 8; ++j) dot += red4[j * 64 + t];
            out[b * 40 + t] = dot + b4[t];
        }
    }
}

extern "C" void kernel_launch(void* const* d_in, const int* in_sizes, int n_in,
                              void* d_out, int out_size, void* d_ws, size_t ws_size,
                              hipStream_t stream) {
    const float* x  = (const float*)d_in[0];
    const float* W1 = (const float*)d_in[2];
    const float* b1 = (const float*)d_in[3];
    const float* g1 = (const float*)d_in[4];
    const float* be1= (const float*)d_in[5];
    const float* rm1= (const float*)d_in[6];
    const float* rv1= (const float*)d_in[7];
    const float* W2 = (const float*)d_in[8];
    const float* b2 = (const float*)d_in[9];
    const float* g2 = (const float*)d_in[10];
    const float* be2= (const float*)d_in[11];
    const float* rm2= (const float*)d_in[12];
    const float* rv2= (const float*)d_in[13];
    const float* W3 = (const float*)d_in[14];
    const float* b3 = (const float*)d_in[15];
    const float* g3 = (const float*)d_in[16];
    const float* be3= (const float*)d_in[17];
    const float* rm3= (const float*)d_in[18];
    const float* rv3= (const float*)d_in[19];
    const float* W4 = (const float*)d_in[20];
    const float* b4 = (const float*)d_in[21];
    float* out = (float*)d_out;

    // ws: bar (3*32 counters, 64B-strided = 6144 B; 8192 reserved) |
    //     part (32*8*815 f32) | h1 (32*512) | h2 (32*256)
    int*   bar  = (int*)d_ws;
    float* part = (float*)((char*)d_ws + 8192);
    float* h1   = part + (size_t)BATCH * NSPLIT * M_POLY;
    float* h2   = h1 + (size_t)BATCH * 512;

    hipMemsetAsync(bar, 0, 6144, stream);
    fused_kernel<<<256, 512, 0, stream>>>(x,
        W1, b1, g1, be1, rm1, rv1,
        W2, b2, g2, be2, rm2, rv2,
        W3, b3, g3, be3, rm3, rv3,
        W4, b4, out, part, h1, h2, bar);
}

// Round 8
// 35.457 us; speedup vs baseline: 4.6257x; 1.7264x over previous
//
#include <hip/hip_runtime.h>
#include <math.h>

#define NPTS   2048
#define BATCH  32
#define M_POLY 815
#define GPB    2
#define NSPLIT 16            // 2048 / (64*GPB)
#define RSTR   192
#define BN_EPS 1e-5f

// ---------------------------------------------------------------------------
// Moments kernel — byte-identical to R4 (measured best: 512 blocks, 2/CU).
// ---------------------------------------------------------------------------
__device__ __forceinline__ bool decode_chunk(int ci, int& Lo, int& k0o, int& co, int& qo) {
    int idx = 0, qoff = 0;
    for (int l = 0; l < 16; ++l) {
        const int nb   = (l + 4) >> 2;
        const int cmin = (l == 0) ? 1 : 0;
        const int nc   = 16 - l - cmin;
        for (int kb = 0; kb < nb; ++kb) {
            if (ci < idx + nc) {
                Lo = l; k0o = kb * 4; co = cmin + (ci - idx);
                qo = 32 + qoff + kb * 4;
                return true;
            }
            idx += nc;
        }
        qoff += nb * 4;
    }
    return false;
}

__global__ __launch_bounds__(256) void moments_kernel(
    const float* __restrict__ x,      // (B, 3, N)
    float*       __restrict__ part)   // (B, NSPLIT, M_POLY)
{
    __shared__ __align__(16) float P[64 * RSTR];   // 49,152 B
    const int t  = threadIdx.x;
    const int sb = blockIdx.x;
    const int b  = blockIdx.y;
    const int nn = t & 63;
    const int qq = t >> 6;
    const int sw = 4 * (nn & 7);
    const int base = nn * RSTR;

    int L, k0, c, qoff4;
    decode_chunk(t, L, k0, c, qoff4);
    const bool dual = (t >= 61 && t <= 63);
    int L2 = 0, k02 = 0, c2 = 0, qoff42 = 32;
    if (dual) decode_chunk(256 + (t - 61), L2, k02, c2, qoff42);

    int qx[8], tx[8], q2x[8], t2x[8];
    #pragma unroll
    for (int r = 0; r < 8; ++r) {
        qx[r]  = qoff4  ^ (4 * r);
        tx[r]  = c      ^ (4 * r);
        q2x[r] = qoff42 ^ (4 * r);
        t2x[r] = c2     ^ (4 * r);
    }

    float a[4]  = {0.f, 0.f, 0.f, 0.f};
    float a2[4] = {0.f, 0.f, 0.f, 0.f};
    const float* xb = x + (size_t)b * 3 * NPTS;

    for (int g = 0; g < GPB; ++g) {
        if (g) __syncthreads();
        {
            const int n = (sb * GPB + g) * 64 + nn;
            const float x1 = xb[NPTS + n], x2 = xb[2 * NPTS + n];
            float T1r[16], T2r[16];
            T1r[0] = 1.f; T1r[1] = x1;
            #pragma unroll
            for (int k = 2; k < 16; ++k) T1r[k] = 2.f * x1 * T1r[k-1] - T1r[k-2];
            T2r[0] = 1.f; T2r[1] = x2;
            #pragma unroll
            for (int k = 2; k < 16; ++k) T2r[k] = 2.f * x2 * T2r[k-1] - T2r[k-2];

            #define QVAL(SS,E) (((E) <= (SS)) ? T1r[((SS)-(E)) & 15] * T2r[(E) & 15] : 0.f)
            #define ROWQ(SS, QO) { \
                _Pragma("unroll") \
                for (int blk2 = 0; blk2 < ((SS)+4)/4; ++blk2) { \
                    float4 v; \
                    v.x = QVAL(SS, 4*blk2+0); v.y = QVAL(SS, 4*blk2+1); \
                    v.z = QVAL(SS, 4*blk2+2); v.w = QVAL(SS, 4*blk2+3); \
                    *(float4*)&P[base + ((32 + (QO) + 4*blk2) ^ sw)] = v; } }

            if (qq == 0) {
                const float x0 = xb[n];
                float T0r[16];
                T0r[0] = 1.f; T0r[1] = x0;
                #pragma unroll
                for (int k = 2; k < 16; ++k) T0r[k] = 2.f * x0 * T0r[k-1] - T0r[k-2];
                #pragma unroll
                for (int blk2 = 0; blk2 < 8; ++blk2) {
                    float4 v;
                    v.x = (4*blk2+0 < 16) ? T0r[(4*blk2+0) & 15] : 0.f;
                    v.y = (4*blk2+1 < 16) ? T0r[(4*blk2+1) & 15] : 0.f;
                    v.z = (4*blk2+2 < 16) ? T0r[(4*blk2+2) & 15] : 0.f;
                    v.w = (4*blk2+3 < 16) ? T0r[(4*blk2+3) & 15] : 0.f;
                    *(float4*)&P[base + ((4*blk2) ^ sw)] = v;
                }
                ROWQ(0, 0)  ROWQ(1, 4)  ROWQ(2, 8)  ROWQ(3, 12)
            } else if (qq == 1) {
                ROWQ(4, 16) ROWQ(5, 24) ROWQ(6, 32) ROWQ(7, 40) ROWQ(8, 48)
            } else if (qq == 2) {
                ROWQ(9, 60) ROWQ(10, 72) ROWQ(11, 84) ROWQ(12, 96)
            } else {
                ROWQ(13, 112) ROWQ(14, 128) ROWQ(15, 144)
            }
            #undef ROWQ
            #undef QVAL
        }
        __syncthreads();

        for (int n8 = 0; n8 < 8; ++n8) {
            const float* rp0 = &P[n8 * 8 * RSTR];
            #pragma unroll
            for (int r = 0; r < 8; ++r) {
                const float* rp = rp0 + r * RSTR;
                const float t0v = rp[tx[r]];
                const float4 q = *(const float4*)&rp[qx[r]];
                a[0] = fmaf(t0v, q.x, a[0]);
                a[1] = fmaf(t0v, q.y, a[1]);
                a[2] = fmaf(t0v, q.z, a[2]);
                a[3] = fmaf(t0v, q.w, a[3]);
                if (dual) {
                    const float u0 = rp[t2x[r]];
                    const float4 p2 = *(const float4*)&rp[q2x[r]];
                    a2[0] = fmaf(u0, p2.x, a2[0]);
                    a2[1] = fmaf(u0, p2.y, a2[1]);
                    a2[2] = fmaf(u0, p2.z, a2[2]);
                    a2[3] = fmaf(u0, p2.w, a2[3]);
                }
            }
        }
    }

    float* pb = part + ((size_t)b * NSPLIT + sb) * M_POLY;
    {
        const int D  = c + L;
        const int mb = D * (D + 1) * (D + 2) / 6 - 1 + L * (L + 1) / 2;
        const int nv = (L - k0 + 1 < 4) ? (L - k0 + 1) : 4;
        #pragma unroll
        for (int i = 0; i < 4; ++i)
            if (i < nv) pb[mb + k0 + i] = a[i];
    }
    if (dual) {
        const int D  = c2 + L2;
        const int mb = D * (D + 1) * (D + 2) / 6 - 1 + L2 * (L2 + 1) / 2;
        const int nv = (L2 - k02 + 1 < 4) ? (L2 - k02 + 1) : 4;
        #pragma unroll
        for (int i = 0; i < 4; ++i)
            if (i < nv) pb[mb + k02 + i] = a2[i];
    }
}

// ---------------------------------------------------------------------------
// Layer 1 — byte-identical to R4. grid (16,32), block 512.
// ---------------------------------------------------------------------------
__global__ __launch_bounds__(512) void l1_kernel(
    const float* __restrict__ part,
    const float* __restrict__ W1, const float* __restrict__ b1,
    const float* __restrict__ g1, const float* __restrict__ be1,
    const float* __restrict__ rm1, const float* __restrict__ rv1,
    float* __restrict__ h1)
{
    __shared__ float fs[816];
    __shared__ float red[16][32];
    const int t  = threadIdx.x;
    const int og = blockIdx.x;
    const int b  = blockIdx.y;

    {
        float s0 = 0.f;
        #pragma unroll
        for (int sp = 0; sp < NSPLIT; ++sp)
            s0 += part[((size_t)b * NSPLIT + sp) * M_POLY + t];
        fs[t] = s0 * (1.0f / (float)NPTS);
        if (t < 303) {
            float s1 = 0.f;
            #pragma unroll
            for (int sp = 0; sp < NSPLIT; ++sp)
                s1 += part[((size_t)b * NSPLIT + sp) * M_POLY + 512 + t];
            fs[512 + t] = s1 * (1.0f / (float)NPTS);
        }
        if (t == 0) fs[815] = 0.f;
    }
    __syncthreads();

    const int o  = og * 32 + (t & 31);
    const int cg = t >> 5;
    const int kb = cg * 51;                 // 16*51 = 816; fs[815]=0 nulls pad
    float acc = 0.f;
    #pragma unroll 8
    for (int kk = 0; kk < 51; ++kk) {
        const int k  = kb + kk;
        const int kr = (k < 815) ? k : 814;
        acc = fmaf(fs[k], W1[(size_t)kr * 512 + o], acc);
    }
    red[cg][t & 31] = acc;
    __syncthreads();

    if (t < 32) {
        float dot = 0.f;
        #pragma unroll
        for (int j = 0; j < 16; ++j) dot += red[j][t];
        const int oo = og * 32 + t;
        const float v = (dot + b1[oo] - rm1[oo]) * g1[oo] * rsqrtf(rv1[oo] + BN_EPS) + be1[oo];
        h1[b * 512 + oo] = v > 0.f ? v : 0.f;
    }
}

// ---------------------------------------------------------------------------
// Layers 2+3+4 merged: one block per batch. 512->256->128->40 all in LDS.
// grid = 32, block 512. W2 streamed once per block (512 KB, ~3 µs L1 time).
// ---------------------------------------------------------------------------
__global__ __launch_bounds__(512) void l234_kernel(
    const float* __restrict__ h1,
    const float* __restrict__ W2, const float* __restrict__ b2,
    const float* __restrict__ g2, const float* __restrict__ be2,
    const float* __restrict__ rm2, const float* __restrict__ rv2,
    const float* __restrict__ W3, const float* __restrict__ b3,
    const float* __restrict__ g3, const float* __restrict__ be3,
    const float* __restrict__ rm3, const float* __restrict__ rv3,
    const float* __restrict__ W4, const float* __restrict__ b4,
    float* __restrict__ out)
{
    __shared__ float S[1536];   // hs[0,512) | red2[512,1024) | h2s[1024,1280)
                                // red3 reuses [0,512) | h3s[1280,1408) | red4 [0,512)
    const int t = threadIdx.x;
    const int b = blockIdx.x;

    float* hs   = S;
    float* red2 = S + 512;
    float* h2s  = S + 1024;
    float* red3 = S;            // hs dead by the time red3 is written
    float* h3s  = S + 1280;
    float* red4 = S;            // red3 dead by the time red4 is written

    hs[t] = h1[b * 512 + t];
    __syncthreads();

    // ---- l2: 256 outputs x 2 k-groups (chain 256) ----
    {
        const int o  = t & 255;
        const int kg = t >> 8;
        const int kb = kg * 256;
        float acc = 0.f;
        #pragma unroll 8
        for (int kk = 0; kk < 256; ++kk)
            acc = fmaf(hs[kb + kk], W2[(size_t)(kb + kk) * 256 + o], acc);
        red2[kg * 256 + o] = acc;
    }
    __syncthreads();
    if (t < 256) {
        const float dot = red2[t] + red2[256 + t];
        const float v = (dot + b2[t] - rm2[t]) * g2[t] * rsqrtf(rv2[t] + BN_EPS) + be2[t];
        h2s[t] = v > 0.f ? v : 0.f;
    }
    __syncthreads();

    // ---- l3: 128 outputs x 4 k-groups (chain 64) ----
    {
        const int o  = t & 127;
        const int kg = t >> 7;
        const int kb = kg * 64;
        float acc = 0.f;
        #pragma unroll 8
        for (int kk = 0; kk < 64; ++kk)
            acc = fmaf(h2s[kb + kk], W3[(size_t)(kb + kk) * 128 + o], acc);
        red3[kg * 128 + o] = acc;
    }
    __syncthreads();
    if (t < 128) {
        const float dot = red3[t] + red3[128 + t] + red3[256 + t] + red3[384 + t];
        const float v = (dot + b3[t] - rm3[t]) * g3[t] * rsqrtf(rv3[t] + BN_EPS) + be3[t];
        h3s[t] = v > 0.f ? v : 0.f;
    }
    __syncthreads();

    // ---- l4: 40 outputs (o<64 lanes, clamp) x 8 k-groups (chain 16) ----
    {
        const int o  = t & 63;
        const int om = (o < 40) ? o : 39;
        const int kg = t >> 6;
        const int kb = kg * 16;
        float acc = 0.f;
        #pragma unroll
        for (int kk = 0; kk < 16; ++kk)
            acc = fmaf(h3s[kb + kk], W4[(size_t)(kb + kk) * 40 + om], acc);
        red4[kg * 64 + o] = acc;
    }
    __syncthreads();
    if (t < 40) {
        float dot = 0.f;
        #pragma unroll
        for (int j = 0; j < 8; ++j) dot += red4[j * 64 + t];
        out[b * 40 + t] = dot + b4[t];
    }
}

extern "C" void kernel_launch(void* const* d_in, const int* in_sizes, int n_in,
                              void* d_out, int out_size, void* d_ws, size_t ws_size,
                              hipStream_t stream) {
    const float* x  = (const float*)d_in[0];
    const float* W1 = (const float*)d_in[2];
    const float* b1 = (const float*)d_in[3];
    const float* g1 = (const float*)d_in[4];
    const float* be1= (const float*)d_in[5];
    const float* rm1= (const float*)d_in[6];
    const float* rv1= (const float*)d_in[7];
    const float* W2 = (const float*)d_in[8];
    const float* b2 = (const float*)d_in[9];
    const float* g2 = (const float*)d_in[10];
    const float* be2= (const float*)d_in[11];
    const float* rm2= (const float*)d_in[12];
    const float* rv2= (const float*)d_in[13];
    const float* W3 = (const float*)d_in[14];
    const float* b3 = (const float*)d_in[15];
    const float* g3 = (const float*)d_in[16];
    const float* be3= (const float*)d_in[17];
    const float* rm3= (const float*)d_in[18];
    const float* rv3= (const float*)d_in[19];
    const float* W4 = (const float*)d_in[20];
    const float* b4 = (const float*)d_in[21];
    float* out = (float*)d_out;

    float* part = (float*)d_ws;                              // 32*16*815 f32
    float* h1   = part + (size_t)BATCH * NSPLIT * M_POLY;    // 32*512

    moments_kernel<<<dim3(NSPLIT, BATCH), 256, 0, stream>>>(x, part);
    l1_kernel<<<dim3(16, BATCH), 512, 0, stream>>>(part,
        W1, b1, g1, be1, rm1, rv1, h1);
    l234_kernel<<<BATCH, 512, 0, stream>>>(h1,
        W2, b2, g2, be2, rm2, rv2,
        W3, b3, g3, be3, rm3, rv3, W4, b4, out);
}

// Round 9
// 32.037 us; speedup vs baseline: 5.1196x; 1.1068x over previous
//
#include <hip/hip_runtime.h>
#include <math.h>

#define NPTS   2048
#define BATCH  32
#define M_POLY 815
#define GPB    2
#define NSPLIT 16            // 2048 / (64*GPB)
#define QSTR   160           // Q words per point row (5 x 32-word frames)
#define T0OFF  10240         // 64*160; T0col[16][64] lives here (+1024 words)
#define BN_EPS 1e-5f

// chunk ci -> (L=e1+e2, k0=e2 block start, c=e0, qoff4=word offset of Q quad)
// ordering: L-major, then k0-block, then c => wave-mates share the quad addr.
__device__ __forceinline__ bool decode_chunk(int ci, int& Lo, int& k0o, int& co, int& qo) {
    int idx = 0, qoff = 0;
    for (int l = 0; l < 16; ++l) {
        const int nb   = (l + 4) >> 2;
        const int cmin = (l == 0) ? 1 : 0;
        const int nc   = 16 - l - cmin;
        for (int kb = 0; kb < nb; ++kb) {
            if (ci < idx + nc) {
                Lo = l; k0o = kb * 4; co = cmin + (ci - idx);
                qo = qoff + kb * 4;
                return true;
            }
            idx += nc;
        }
        qoff += nb * 4;
    }
    return false;
}

// ---------------------------------------------------------------------------
// Moments kernel. grid (NSPLIT, BATCH), block 256, 2 blocks/CU (45 KB LDS).
// Phase A: per 64-point group, build swizzled Q rows (pair products T1*T2,
// anti-diagonal layout) + T0col[c][(n+4c)&63] (column layout, rotated).
// Phase B: thread = one 4-chunk of monomials; per 4 points: 1 b128 T0col
// quad + 4 b128 Q quads (was 4 b32 + 4 b128). Chunks 256-258 (e0=0, T0=1)
// ride on lanes 253-255 with Q-only reads.
// ---------------------------------------------------------------------------
__global__ __launch_bounds__(256) void moments_kernel(
    const float* __restrict__ x,      // (B, 3, N)
    float*       __restrict__ part)   // (B, NSPLIT, M_POLY)
{
    __shared__ __align__(16) float P[64 * QSTR + 1024];   // 45,056 B
    const int t  = threadIdx.x;
    const int sb = blockIdx.x;
    const int b  = blockIdx.y;
    const int nn = t & 63;
    const int qq = t >> 6;
    const int sw = 4 * (nn & 7);
    const int base = nn * QSTR;

    int L, k0, c, qoff4;
    decode_chunk(t, L, k0, c, qoff4);
    // leftover chunks 256..258 = (L=15, c=0, k0=4/8/12) on lanes 253..255
    const bool dual = (t >= 253);
    const int k02   = dual ? 4 * (t - 252) : 4;
    const int qoff42 = 144 + k02;            // Qoff(L=15)=144

    int qx[8], q2x[8];
    #pragma unroll
    for (int r = 0; r < 8; ++r) {
        qx[r]  = qoff4  ^ (4 * r);
        q2x[r] = qoff42 ^ (4 * r);
    }

    float a[4]  = {0.f, 0.f, 0.f, 0.f};
    float a2[4] = {0.f, 0.f, 0.f, 0.f};
    const float* xb = x + (size_t)b * 3 * NPTS;

    for (int g = 0; g < GPB; ++g) {
        if (g) __syncthreads();
        {   // ---------------- phase A ----------------
            const int n = (sb * GPB + g) * 64 + nn;
            const float x1 = xb[NPTS + n], x2 = xb[2 * NPTS + n];
            float T1r[16], T2r[16];
            T1r[0] = 1.f; T1r[1] = x1;
            #pragma unroll
            for (int k = 2; k < 16; ++k) T1r[k] = 2.f * x1 * T1r[k-1] - T1r[k-2];
            T2r[0] = 1.f; T2r[1] = x2;
            #pragma unroll
            for (int k = 2; k < 16; ++k) T2r[k] = 2.f * x2 * T2r[k-1] - T2r[k-2];

            #define QVAL(SS,E) (((E) <= (SS)) ? T1r[((SS)-(E)) & 15] * T2r[(E) & 15] : 0.f)
            #define ROWQ(SS, QO) { \
                _Pragma("unroll") \
                for (int blk2 = 0; blk2 < ((SS)+4)/4; ++blk2) { \
                    float4 v; \
                    v.x = QVAL(SS, 4*blk2+0); v.y = QVAL(SS, 4*blk2+1); \
                    v.z = QVAL(SS, 4*blk2+2); v.w = QVAL(SS, 4*blk2+3); \
                    *(float4*)&P[base + (((QO) + 4*blk2) ^ sw)] = v; } }

            if (qq == 0) {
                const float x0 = xb[n];
                float T0r[16];
                T0r[0] = 1.f; T0r[1] = x0;
                #pragma unroll
                for (int k = 2; k < 16; ++k) T0r[k] = 2.f * x0 * T0r[k-1] - T0r[k-2];
                #pragma unroll
                for (int cc = 0; cc < 16; ++cc)
                    P[T0OFF + cc * 64 + ((nn + 4 * cc) & 63)] = T0r[cc];
                ROWQ(0, 0)  ROWQ(1, 4)  ROWQ(2, 8)  ROWQ(3, 12)
            } else if (qq == 1) {
                ROWQ(4, 16) ROWQ(5, 24) ROWQ(6, 32) ROWQ(7, 40) ROWQ(8, 48)
            } else if (qq == 2) {
                ROWQ(9, 60) ROWQ(10, 72) ROWQ(11, 84) ROWQ(12, 96)
            } else {
                ROWQ(13, 112) ROWQ(14, 128) ROWQ(15, 144)
            }
            #undef ROWQ
            #undef QVAL
        }
        __syncthreads();

        // ---------------- phase B ----------------
        #pragma unroll 4
        for (int q4 = 0; q4 < 16; ++q4) {
            const int np0 = q4 * 4;
            const float4 t0q =
                *(const float4*)&P[T0OFF + c * 64 + ((np0 + 4 * c) & 63)];
            #pragma unroll
            for (int i = 0; i < 4; ++i) {
                const int np = np0 + i;
                const float* rp = &P[np * QSTR];
                const float  t0v = ((const float*)&t0q)[i];
                const float4 qv = *(const float4*)&rp[qx[np & 7]];
                a[0] = fmaf(t0v, qv.x, a[0]);
                a[1] = fmaf(t0v, qv.y, a[1]);
                a[2] = fmaf(t0v, qv.z, a[2]);
                a[3] = fmaf(t0v, qv.w, a[3]);
                if (dual) {           // e0=0 -> T0 = 1, Q-only accumulate
                    const float4 p2 = *(const float4*)&rp[q2x[np & 7]];
                    a2[0] += p2.x; a2[1] += p2.y; a2[2] += p2.z; a2[3] += p2.w;
                }
            }
        }
    }

    // store: m = tet(D)-1 + L(L+1)/2 + e2, consecutive in e2
    float* pb = part + ((size_t)b * NSPLIT + sb) * M_POLY;
    {
        const int D  = c + L;
        const int mb = D * (D + 1) * (D + 2) / 6 - 1 + L * (L + 1) / 2;
        const int nv = (L - k0 + 1 < 4) ? (L - k0 + 1) : 4;
        #pragma unroll
        for (int i = 0; i < 4; ++i)
            if (i < nv) pb[mb + k0 + i] = a[i];
    }
    if (dual) {
        const int mb = 799;          // D=15, L=15 base
        #pragma unroll
        for (int i = 0; i < 4; ++i)
            pb[mb + k02 + i] = a2[i];
    }
}

// ---------------------------------------------------------------------------
// Layer 1: reduce partials + 815->512 + BN + ReLU.
// grid = (8, 32), block 512 = 64 outputs x 8 k-groups (chains of 102).
// (R2-proven config; halves part re-read traffic vs 16 groups.)
// ---------------------------------------------------------------------------
__global__ __launch_bounds__(512) void l1_kernel(
    const float* __restrict__ part,
    const float* __restrict__ W1, const float* __restrict__ b1,
    const float* __restrict__ g1, const float* __restrict__ be1,
    const float* __restrict__ rm1, const float* __restrict__ rv1,
    float* __restrict__ h1)
{
    __shared__ float fs[816];
    __shared__ float red[8][64];
    const int t  = threadIdx.x;
    const int og = blockIdx.x;
    const int b  = blockIdx.y;

    {
        float s0 = 0.f;
        #pragma unroll
        for (int sp = 0; sp < NSPLIT; ++sp)
            s0 += part[((size_t)b * NSPLIT + sp) * M_POLY + t];
        fs[t] = s0 * (1.0f / (float)NPTS);
        if (t < 303) {
            float s1 = 0.f;
            #pragma unroll
            for (int sp = 0; sp < NSPLIT; ++sp)
                s1 += part[((size_t)b * NSPLIT + sp) * M_POLY + 512 + t];
            fs[512 + t] = s1 * (1.0f / (float)NPTS);
        }
        if (t == 0) fs[815] = 0.f;
    }
    __syncthreads();

    const int o  = og * 64 + (t & 63);
    const int cg = t >> 6;
    const int kb = cg * 102;               // 8*102 = 816; fs[815]=0 nulls pad
    float acc = 0.f;
    #pragma unroll 6
    for (int kk = 0; kk < 102; ++kk) {
        const int k  = kb + kk;
        const int kr = (k < 815) ? k : 814;
        acc = fmaf(fs[k], W1[(size_t)kr * 512 + o], acc);
    }
    red[cg][t & 63] = acc;
    __syncthreads();

    if (t < 64) {
        float dot = 0.f;
        #pragma unroll
        for (int j = 0; j < 8; ++j) dot += red[j][t];
        const int oo = og * 64 + t;
        const float v = (dot + b1[oo] - rm1[oo]) * g1[oo] * rsqrtf(rv1[oo] + BN_EPS) + be1[oo];
        h1[b * 512 + oo] = v > 0.f ? v : 0.f;
    }
}

// ---------------------------------------------------------------------------
// Layer 2 — byte-identical to R4. grid (8, 32), block 512 = 32 o x 16 kg.
// ---------------------------------------------------------------------------
__global__ __launch_bounds__(512) void l2_kernel(
    const float* __restrict__ h1,
    const float* __restrict__ W2, const float* __restrict__ b2,
    const float* __restrict__ g2, const float* __restrict__ be2,
    const float* __restrict__ rm2, const float* __restrict__ rv2,
    float* __restrict__ h2)
{
    __shared__ float hs[512];
    __shared__ float red[16][32];
    const int t  = threadIdx.x;
    const int og = blockIdx.x;
    const int b  = blockIdx.y;

    hs[t] = h1[b * 512 + t];
    __syncthreads();

    const int o  = og * 32 + (t & 31);
    const int cg = t >> 5;
    const int kb = cg * 32;
    float acc = 0.f;
    #pragma unroll
    for (int kk = 0; kk < 32; ++kk)
        acc = fmaf(hs[kb + kk], W2[(size_t)(kb + kk) * 256 + o], acc);
    red[cg][t & 31] = acc;
    __syncthreads();

    if (t < 32) {
        float dot = 0.f;
        #pragma unroll
        for (int j = 0; j < 16; ++j) dot += red[j][t];
        const int oo = og * 32 + t;
        const float v = (dot + b2[oo] - rm2[oo]) * g2[oo] * rsqrtf(rv2[oo] + BN_EPS) + be2[oo];
        h2[b * 256 + oo] = v > 0.f ? v : 0.f;
    }
}

// ---------------------------------------------------------------------------
// Layers 3+4 — byte-identical to R4. grid = 32, block 512.
// ---------------------------------------------------------------------------
__global__ __launch_bounds__(512) void l34_kernel(
    const float* __restrict__ h2,
    const float* __restrict__ W3, const float* __restrict__ b3,
    const float* __restrict__ g3, const float* __restrict__ be3,
    const float* __restrict__ rm3, const float* __restrict__ rv3,
    const float* __restrict__ W4, const float* __restrict__ b4,
    float* __restrict__ out)
{
    __shared__ float hs[256];
    __shared__ float red3[4][128];
    __shared__ float h3s[128];
    __shared__ float red4[8][64];
    const int t = threadIdx.x;
    const int b = blockIdx.x;

    if (t < 256) hs[t] = h2[b * 256 + t];
    __syncthreads();

    {
        const int o  = t & 127;
        const int cg = t >> 7;
        const int kb = cg * 64;
        float acc = 0.f;
        #pragma unroll 8
        for (int kk = 0; kk < 64; ++kk)
            acc = fmaf(hs[kb + kk], W3[(size_t)(kb + kk) * 128 + o], acc);
        red3[cg][o] = acc;
    }
    __syncthreads();
    if (t < 128) {
        const float dot = red3[0][t] + red3[1][t] + red3[2][t] + red3[3][t];
        const float v = (dot + b3[t] - rm3[t]) * g3[t] * rsqrtf(rv3[t] + BN_EPS) + be3[t];
        h3s[t] = v > 0.f ? v : 0.f;
    }
    __syncthreads();

    {
        const int o  = t & 63;
        const int om = (o < 40) ? o : 39;
        const int cg = t >> 6;
        const int kb = cg * 16;
        float acc = 0.f;
        #pragma unroll
        for (int kk = 0; kk < 16; ++kk)
            acc = fmaf(h3s[kb + kk], W4[(size_t)(kb + kk) * 40 + om], acc);
        red4[cg][o] = acc;
    }
    __syncthreads();
    if (t < 40) {
        float dot = 0.f;
        #pragma unroll
        for (int j = 0; j < 8; ++j) dot += red4[j][t];
        out[b * 40 + t] = dot + b4[t];
    }
}

extern "C" void kernel_launch(void* const* d_in, const int* in_sizes, int n_in,
                              void* d_out, int out_size, void* d_ws, size_t ws_size,
                              hipStream_t stream) {
    const float* x  = (const float*)d_in[0];
    const float* W1 = (const float*)d_in[2];
    const float* b1 = (const float*)d_in[3];
    const float* g1 = (const float*)d_in[4];
    const float* be1= (const float*)d_in[5];
    const float* rm1= (const float*)d_in[6];
    const float* rv1= (const float*)d_in[7];
    const float* W2 = (const float*)d_in[8];
    const float* b2 = (const float*)d_in[9];
    const float* g2 = (const float*)d_in[10];
    const float* be2= (const float*)d_in[11];
    const float* rm2= (const float*)d_in[12];
    const float* rv2= (const float*)d_in[13];
    const float* W3 = (const float*)d_in[14];
    const float* b3 = (const float*)d_in[15];
    const float* g3 = (const float*)d_in[16];
    const float* be3= (const float*)d_in[17];
    const float* rm3= (const float*)d_in[18];
    const float* rv3= (const float*)d_in[19];
    const float* W4 = (const float*)d_in[20];
    const float* b4 = (const float*)d_in[21];
    float* out = (float*)d_out;

    float* part = (float*)d_ws;                              // 32*16*815 f32
    float* h1   = part + (size_t)BATCH * NSPLIT * M_POLY;    // 32*512
    float* h2   = h1 + (size_t)BATCH * 512;                  // 32*256

    moments_kernel<<<dim3(NSPLIT, BATCH), 256, 0, stream>>>(x, part);
    l1_kernel<<<dim3(8, BATCH), 512, 0, stream>>>(part,
        W1, b1, g1, be1, rm1, rv1, h1);
    l2_kernel<<<dim3(8, BATCH), 512, 0, stream>>>(h1,
        W2, b2, g2, be2, rm2, rv2, h2);
    l34_kernel<<<BATCH, 512, 0, stream>>>(h2,
        W3, b3, g3, be3, rm3, rv3, W4, b4, out);
}